// Round 18
// baseline (477.625 us; speedup 1.0000x reference)
//
#include <hip/hip_runtime.h>
#include <stdint.h>

#define T_LEN    1048576
#define TY_LEN   1048561
#define OUT_W    1048562
#define NM       32
#define WIN      16
#define NBLK     4096    // conv blocks == 256-step chunks
#define CBT      256     // conv block threads (4 waves)
#define TPB      256     // timesteps per conv block (8 subchunks of 32)
#define XS_W     272     // 256 + 15 halo + pad; 32*272*4 = 34816 B
#define NF4      68      // XS_W/4 float4s per channel
#define ID8      0xE4u   // identity map, 2-bit packed: 0|1<<2|2<<4|3<<6
#define FLG_AGG  0x40000000u
#define FLG_INC  0x80000000u

__device__ inline float sgnf(float a){
    return (a > 0.0f) ? 1.0f : ((a < 0.0f) ? -1.0f : 0.0f);
}

// 2-bit-packed 4-state map composition: (f o g)(s) = f(g(s))
__device__ inline uint32_t comp2(uint32_t f, uint32_t g){
    uint32_t r = 0;
#pragma unroll
    for (int k = 0; k < 4; ++k) {
        const uint32_t s = (g >> (2 * k)) & 3u;
        r |= ((f >> (2 * s)) & 3u) << (2 * k);
    }
    return r;
}

// async global->LDS, 16 B per lane (VMEM/vmcnt path; LDS dst linear per lane)
__device__ inline void gload16(const void* g, void* l){
    __builtin_amdgcn_global_load_lds(
        (const __attribute__((address_space(1))) unsigned int*)g,
        (__attribute__((address_space(3))) unsigned int*)l, 16, 0, 0);
}

// ---------------- weight relayout w[o][i][h] -> wT2[h][og][i][oi] + agg clear
__global__ void wtrans_kernel(const float* __restrict__ w, float* __restrict__ wT2,
                              uint32_t* __restrict__ agg){
    const int idx = blockIdx.x * 256 + threadIdx.x;
    if (idx < NM * NM * WIN) {
        const int o = idx / (NM * WIN);
        const int r = idx - o * (NM * WIN);
        const int i = r / WIN;
        const int h = r - i * WIN;
        wT2[(((h * 4) + (o >> 3)) * NM + i) * 8 + (o & 7)] = w[idx];
    }
    for (int j = idx; j < NM * NBLK; j += 64 * 256) agg[j] = 0;
}

// ---------------- fully fused: conv + scan maps + decoupled lookback + tanh.
// Weights double-buffered in LDS per h-slice (pure-ds in-order K-loop, no
// scalar-load drains). Conv order XLA-CPU-faithful (h-major, i-minor, bias
// last); FMA chain operand-identical to all passing rounds.
__global__ __launch_bounds__(256, 3) void conv_kernel(
    const float* __restrict__ x, const float* __restrict__ wT2,
    const float* __restrict__ b, const float* __restrict__ sp,
    const float* __restrict__ pwv, float* __restrict__ out,
    uint32_t* __restrict__ agg)
{
    __shared__ float xs[NM * XS_W];     // staging; reused as y-stage [256][33]
    __shared__ float wlds[2][1024];     // h-slice weight double buffer (8 KiB)
    __shared__ uint32_t maps8[256];     // 8-bit local maps per (market, subchunk)
    const int bid  = blockIdx.x;
    const int base = bid * TPB;
    const int tid  = threadIdx.x;
    // ---- x staging ----
    if (bid != NBLK - 1) {
        for (int idx = tid; idx < NM * NF4; idx += CBT) {
            const int i = idx / NF4;
            const int q = idx - i * NF4;
            gload16(x + (size_t)i * T_LEN + base + q * 4, &xs[idx * 4]);
        }
    } else {
        for (int idx = tid; idx < NM * NF4; idx += CBT) {
            const int i = idx / NF4;
            const int q = idx - i * NF4;
            const int t0 = base + q * 4;
            float4 v;
            v.x = (t0 + 0 < T_LEN) ? x[(size_t)i * T_LEN + t0 + 0] : 0.0f;
            v.y = (t0 + 1 < T_LEN) ? x[(size_t)i * T_LEN + t0 + 1] : 0.0f;
            v.z = (t0 + 2 < T_LEN) ? x[(size_t)i * T_LEN + t0 + 2] : 0.0f;
            v.w = (t0 + 3 < T_LEN) ? x[(size_t)i * T_LEN + t0 + 3] : 0.0f;
            *reinterpret_cast<float4*>(&xs[i * XS_W + q * 4]) = v;
        }
    }
    // ---- weight prologue: h=0 slice -> wlds[0] ----
    gload16(wT2 + tid * 4, &wlds[0][tid * 4]);
    const int lane = tid & 63;
    const int og   = __builtin_amdgcn_readfirstlane(tid >> 6);
    float acc[8][4];
#pragma unroll
    for (int oi = 0; oi < 8; ++oi)
#pragma unroll
        for (int tt = 0; tt < 4; ++tt) acc[oi][tt] = 0.0f;
#pragma unroll 1
    for (int h = 0; h < WIN; ++h) {
        asm volatile("s_waitcnt vmcnt(0)" ::: "memory");   // h-slice landed
        __syncthreads();                                    // all waves' slices
        if (h + 1 < WIN)
            gload16(wT2 + (size_t)(h + 1) * 1024 + tid * 4,
                    &wlds[(h + 1) & 1][tid * 4]);
        const float* wb = &wlds[h & 1][og * 256];          // lane-uniform
#pragma unroll 1
        for (int c = 0; c < 4; ++c) {            // 8-i chunks
            float xv[8][4];
#pragma unroll
            for (int i2 = 0; i2 < 8; ++i2) {
                const int i = c * 8 + i2;
#pragma unroll
                for (int tt = 0; tt < 4; ++tt)
                    xv[i2][tt] = xs[i * XS_W + lane + 64 * tt + h];
            }
#pragma unroll
            for (int i2 = 0; i2 < 8; ++i2) {
                const float* wr = wb + (c * 8 + i2) * 8;   // ds_read_b128 x2
                const float4 w0 = *reinterpret_cast<const float4*>(wr);
                const float4 w1 = *reinterpret_cast<const float4*>(wr + 4);
#pragma unroll
                for (int tt = 0; tt < 4; ++tt) {
                    acc[0][tt] = fmaf(w0.x, xv[i2][tt], acc[0][tt]);
                    acc[1][tt] = fmaf(w0.y, xv[i2][tt], acc[1][tt]);
                    acc[2][tt] = fmaf(w0.z, xv[i2][tt], acc[2][tt]);
                    acc[3][tt] = fmaf(w0.w, xv[i2][tt], acc[3][tt]);
                    acc[4][tt] = fmaf(w1.x, xv[i2][tt], acc[4][tt]);
                    acc[5][tt] = fmaf(w1.y, xv[i2][tt], acc[5][tt]);
                    acc[6][tt] = fmaf(w1.z, xv[i2][tt], acc[6][tt]);
                    acc[7][tt] = fmaf(w1.w, xv[i2][tt], acc[7][tt]);
                }
            }
        }
    }
    // ---- y = acc + bias -> LDS y-stage, subchunk-padded stride 33 ----
    __syncthreads();   // staging reads of xs complete before overwrite
#pragma unroll
    for (int oi = 0; oi < 8; ++oi) {
        const int o = og * 8 + oi;
        const float bv = b[o];
#pragma unroll
        for (int tt = 0; tt < 4; ++tt) {
            const int sub = (lane >> 5) + 2 * tt;          // t_local/32
            xs[(o * 8 + sub) * 33 + (lane & 31)] = acc[oi][tt] + bv;
        }
    }
    __syncthreads();
    // ---- local 32-step maps: thread = (market sm, subchunk ss) ----
    const int sm = tid >> 3;
    const int ss = tid & 7;
    const float pws = pwv[sm];
    const float spv = sp[sm];
    int st = TY_LEN - base - ss * 32;
    st = st < 0 ? 0 : (st > 32 ? 32 : st);
    {
        float q0 = -1.0f, q1 = 0.0f, q2 = 1.0f, q3 = spv;
        const float* yr = &xs[(sm * 8 + ss) * 33];
        for (int j = 0; j < st; ++j) {
            const float hv = yr[j];
            q0 = sgnf(fmaf(q0, pws, hv));
            q1 = sgnf(fmaf(q1, pws, hv));
            q2 = sgnf(fmaf(q2, pws, hv));
            q3 = sgnf(fmaf(q3, pws, hv));
        }
        const uint32_t e0 = (uint32_t)((int)q0 + 1);
        const uint32_t e1 = (uint32_t)((int)q1 + 1);
        const uint32_t e2 = (uint32_t)((int)q2 + 1);
        const uint32_t e3 = (st == 0) ? 3u : (uint32_t)((int)q3 + 1);
        maps8[tid] = e0 | (e1 << 2) | (e2 << 4) | (e3 << 6);
    }
    __syncthreads();
    // ---- publish AGGREGATE (flag bit30) ----
    uint32_t* ar = agg + (size_t)sm * NBLK;
    if (ss == 0) {
        uint32_t seg = ID8;
#pragma unroll
        for (int s2 = 0; s2 < 8; ++s2) seg = comp2(maps8[sm * 8 + s2], seg);
        __hip_atomic_store(&ar[bid], FLG_AGG | seg,
                           __ATOMIC_RELAXED, __HIP_MEMORY_SCOPE_AGENT);
    }
    // ---- decoupled lookback: 8-wide windows, stop at first INCLUSIVE ----
    uint32_t prefix = ID8;
    {
        int wstart = bid - 8;
        bool done = (bid == 0);
        while (!done) {
            const int idx = wstart + ss;
            uint32_t w;
            if (idx < 0) {
                w = FLG_INC | ID8;
            } else {
                w = __hip_atomic_load(&ar[idx], __ATOMIC_RELAXED,
                                      __HIP_MEMORY_SCOPE_AGENT);
                while (!(w & 0xC0000000u)) {
                    __builtin_amdgcn_s_sleep(1);
                    w = __hip_atomic_load(&ar[idx], __ATOMIC_RELAXED,
                                          __HIP_MEMORY_SCOPE_AGENT);
                }
            }
            uint32_t cur = prefix;
            bool stop = false;
#pragma unroll
            for (int k = 7; k >= 0; --k) {
                const uint32_t wk = __shfl(w, (tid & 56) | k, 64);
                if (!stop) {
                    cur = comp2(cur, wk & 0xFFu);
                    if (wk & FLG_INC) stop = true;
                }
            }
            prefix = cur;
            done = stop;
            wstart -= 8;
        }
    }
    // ---- publish INCLUSIVE (flag bit31) ----
    if (ss == 0) {
        uint32_t Aown = ID8;
#pragma unroll
        for (int s2 = 0; s2 < 8; ++s2) Aown = comp2(maps8[sm * 8 + s2], Aown);
        __hip_atomic_store(&ar[bid], FLG_INC | comp2(Aown, prefix),
                           __ATOMIC_RELAXED, __HIP_MEMORY_SCOPE_AGENT);
    }
    // ---- within-block entry + sequential tanh over this subchunk (in LDS) ----
    {
        uint32_t s = (prefix >> 6) & 3u;   // prefix applied to initial state 3
        for (int k = 0; k < ss; ++k) s = (maps8[sm * 8 + k] >> (2 * s)) & 3u;
        float p = (s == 3u) ? spv : ((float)(int)s - 1.0f);
        float* yr = &xs[(sm * 8 + ss) * 33];
        for (int j = 0; j < st; ++j) {
            const float a = fmaf(p, pws, yr[j]);
            yr[j] = tanhf(a);
            p = sgnf(a);
        }
    }
    __syncthreads();
    // ---- coalesced final store (conv layout) ----
#pragma unroll
    for (int oi = 0; oi < 8; ++oi) {
        const int o = og * 8 + oi;
        float* orow = out + (size_t)o * OUT_W + 1 + base + lane;
#pragma unroll
        for (int tt = 0; tt < 4; ++tt) {
            const int t = base + lane + 64 * tt;
            const int sub = (lane >> 5) + 2 * tt;
            if (t < TY_LEN) orow[64 * tt] = xs[(o * 8 + sub) * 33 + (lane & 31)];
        }
    }
    if (bid == 0 && tid < NM)
        out[(size_t)tid * OUT_W] = sp[tid];
}

extern "C" void kernel_launch(void* const* d_in, const int* in_sizes, int n_in,
                              void* d_out, int out_size, void* d_ws, size_t ws_size,
                              hipStream_t stream)
{
    const float* x   = (const float*)d_in[0];
    const float* spv = (const float*)d_in[1];
    const float* w   = (const float*)d_in[2];
    const float* b   = (const float*)d_in[3];
    const float* pw  = (const float*)d_in[4];
    float* out = (float*)d_out;

    // workspace: wT2 64 KiB | agg 512 KiB (flag-tagged maps)
    uint8_t* ws = (uint8_t*)d_ws;
    float*    wT2 = (float*)ws;
    uint32_t* agg = (uint32_t*)(ws + 65536);

    wtrans_kernel<<<64, 256, 0, stream>>>(w, wT2, agg);
    conv_kernel<<<NBLK, CBT, 0, stream>>>(x, wT2, b, spv, pw, out, agg);
}

// Round 19
// 471.006 us; speedup vs baseline: 1.0141x; 1.0141x over previous
//
#include <hip/hip_runtime.h>
#include <stdint.h>

#define T_LEN    1048576
#define TY_LEN   1048561
#define OUT_W    1048562
#define NM       32
#define WIN      16
#define NBLK     4096    // conv blocks == 256-step chunks
#define CBT      256     // conv block threads (4 waves)
#define TPB      256     // timesteps per conv block (8 subchunks of 32)
#define XS_W     272     // 256 + 15 halo + pad; 32*272*4 = 34816 B
#define NF4      68     // XS_W/4 float4s per channel
#define ID8      0xE4u   // identity map, 2-bit packed: 0|1<<2|2<<4|3<<6
#define FLG_AGG  0x40000000u
#define FLG_INC  0x80000000u

__device__ inline float sgnf(float a){
    return (a > 0.0f) ? 1.0f : ((a < 0.0f) ? -1.0f : 0.0f);
}

// 2-bit-packed 4-state map composition: (f o g)(s) = f(g(s))
__device__ inline uint32_t comp2(uint32_t f, uint32_t g){
    uint32_t r = 0;
#pragma unroll
    for (int k = 0; k < 4; ++k) {
        const uint32_t s = (g >> (2 * k)) & 3u;
        r |= ((f >> (2 * s)) & 3u) << (2 * k);
    }
    return r;
}

// async global->LDS, 16 B per lane (VMEM/vmcnt path; LDS dst linear per lane)
__device__ inline void gload16(const void* g, void* l){
    __builtin_amdgcn_global_load_lds(
        (const __attribute__((address_space(1))) unsigned int*)g,
        (__attribute__((address_space(3))) unsigned int*)l, 16, 0, 0);
}

// ---------------- weight relayout w[o][i][h] -> wT2[h][og][i][oi] + agg clear
__global__ void wtrans_kernel(const float* __restrict__ w, float* __restrict__ wT2,
                              uint32_t* __restrict__ agg){
    const int idx = blockIdx.x * 256 + threadIdx.x;
    if (idx < NM * NM * WIN) {
        const int o = idx / (NM * WIN);
        const int r = idx - o * (NM * WIN);
        const int i = r / WIN;
        const int h = r - i * WIN;
        wT2[(((h * 4) + (o >> 3)) * NM + i) * 8 + (o & 7)] = w[idx];
    }
    for (int j = idx; j < NM * NBLK; j += 64 * 256) agg[j] = 0;
}

// ---------------- fully fused: conv + scan maps + decoupled lookback + tanh.
// Weights staged per-h-slice into a single 4 KiB LDS buffer (pure-ds in-order
// K-loop; no scalar-load drains) -- LDS total 38912 B keeps 4 blocks/CU.
// Conv order XLA-CPU-faithful (h-major, i-minor, bias last); FMA chain
// operand-identical to all passing rounds. y lives only in LDS.
__global__ __launch_bounds__(256, 4) void conv_kernel(
    const float* __restrict__ x, const float* __restrict__ wT2,
    const float* __restrict__ b, const float* __restrict__ sp,
    const float* __restrict__ pwv, float* __restrict__ out,
    uint32_t* __restrict__ agg)
{
    __shared__ float xs[NM * XS_W];     // staging; reused as y-stage [256][33]
    __shared__ float wlds[1024];        // single h-slice weight buffer (4 KiB)
    uint32_t* maps8 = (uint32_t*)wlds;  // aliased after weights are dead
    const int bid  = blockIdx.x;
    const int base = bid * TPB;
    const int tid  = threadIdx.x;
    // ---- x staging (async to LDS; last block takes the guarded VGPR path) ----
    if (bid != NBLK - 1) {
        for (int idx = tid; idx < NM * NF4; idx += CBT) {
            const int i = idx / NF4;
            const int q = idx - i * NF4;
            gload16(x + (size_t)i * T_LEN + base + q * 4, &xs[i * XS_W + q * 4]);
        }
    } else {
        for (int idx = tid; idx < NM * NF4; idx += CBT) {
            const int i = idx / NF4;
            const int q = idx - i * NF4;
            const int t0 = base + q * 4;
            float4 v;
            v.x = (t0 + 0 < T_LEN) ? x[(size_t)i * T_LEN + t0 + 0] : 0.0f;
            v.y = (t0 + 1 < T_LEN) ? x[(size_t)i * T_LEN + t0 + 1] : 0.0f;
            v.z = (t0 + 2 < T_LEN) ? x[(size_t)i * T_LEN + t0 + 2] : 0.0f;
            v.w = (t0 + 3 < T_LEN) ? x[(size_t)i * T_LEN + t0 + 3] : 0.0f;
            *reinterpret_cast<float4*>(&xs[i * XS_W + q * 4]) = v;
        }
    }
    // ---- weight prologue: h=0 slice ----
    gload16(wT2 + tid * 4, &wlds[tid * 4]);
    const int lane = tid & 63;
    const int og   = __builtin_amdgcn_readfirstlane(tid >> 6);
    float acc[8][4];
#pragma unroll
    for (int oi = 0; oi < 8; ++oi)
#pragma unroll
        for (int tt = 0; tt < 4; ++tt) acc[oi][tt] = 0.0f;
#pragma unroll 1
    for (int h = 0; h < WIN; ++h) {
        asm volatile("s_waitcnt vmcnt(0)" ::: "memory");   // slice h landed
        __syncthreads();
        const float* wb = &wlds[og * 256];                 // lane-uniform base
#pragma unroll 1
        for (int c = 0; c < 4; ++c) {            // 8-i chunks
            float xv[8][4];
#pragma unroll
            for (int i2 = 0; i2 < 8; ++i2) {
                const int i = c * 8 + i2;
#pragma unroll
                for (int tt = 0; tt < 4; ++tt)
                    xv[i2][tt] = xs[i * XS_W + lane + 64 * tt + h];
            }
#pragma unroll
            for (int i2 = 0; i2 < 8; ++i2) {
                const float* wr = wb + (c * 8 + i2) * 8;   // ds_read_b128 x2
                const float4 w0 = *reinterpret_cast<const float4*>(wr);
                const float4 w1 = *reinterpret_cast<const float4*>(wr + 4);
#pragma unroll
                for (int tt = 0; tt < 4; ++tt) {
                    acc[0][tt] = fmaf(w0.x, xv[i2][tt], acc[0][tt]);
                    acc[1][tt] = fmaf(w0.y, xv[i2][tt], acc[1][tt]);
                    acc[2][tt] = fmaf(w0.z, xv[i2][tt], acc[2][tt]);
                    acc[3][tt] = fmaf(w0.w, xv[i2][tt], acc[3][tt]);
                    acc[4][tt] = fmaf(w1.x, xv[i2][tt], acc[4][tt]);
                    acc[5][tt] = fmaf(w1.y, xv[i2][tt], acc[5][tt]);
                    acc[6][tt] = fmaf(w1.z, xv[i2][tt], acc[6][tt]);
                    acc[7][tt] = fmaf(w1.w, xv[i2][tt], acc[7][tt]);
                }
            }
        }
        __syncthreads();                                    // wlds reads done
        if (h + 1 < WIN)
            gload16(wT2 + (size_t)(h + 1) * 1024 + tid * 4, &wlds[tid * 4]);
    }
    // ---- y = acc + bias -> LDS y-stage, subchunk-padded stride 33 ----
#pragma unroll
    for (int oi = 0; oi < 8; ++oi) {
        const int o = og * 8 + oi;
        const float bv = b[o];
#pragma unroll
        for (int tt = 0; tt < 4; ++tt) {
            const int sub = (lane >> 5) + 2 * tt;          // t_local/32
            xs[(o * 8 + sub) * 33 + (lane & 31)] = acc[oi][tt] + bv;
        }
    }
    __syncthreads();
    // ---- local 32-step maps: thread = (market sm, subchunk ss) ----
    const int sm = tid >> 3;
    const int ss = tid & 7;
    const float pws = pwv[sm];
    const float spv = sp[sm];
    int st = TY_LEN - base - ss * 32;
    st = st < 0 ? 0 : (st > 32 ? 32 : st);
    {
        float q0 = -1.0f, q1 = 0.0f, q2 = 1.0f, q3 = spv;
        const float* yr = &xs[(sm * 8 + ss) * 33];
        for (int j = 0; j < st; ++j) {
            const float hv = yr[j];
            q0 = sgnf(fmaf(q0, pws, hv));
            q1 = sgnf(fmaf(q1, pws, hv));
            q2 = sgnf(fmaf(q2, pws, hv));
            q3 = sgnf(fmaf(q3, pws, hv));
        }
        const uint32_t e0 = (uint32_t)((int)q0 + 1);
        const uint32_t e1 = (uint32_t)((int)q1 + 1);
        const uint32_t e2 = (uint32_t)((int)q2 + 1);
        const uint32_t e3 = (st == 0) ? 3u : (uint32_t)((int)q3 + 1);
        maps8[tid] = e0 | (e1 << 2) | (e2 << 4) | (e3 << 6);
    }
    __syncthreads();
    // ---- publish AGGREGATE (flag bit30) ----
    uint32_t* ar = agg + (size_t)sm * NBLK;
    if (ss == 0) {
        uint32_t seg = ID8;
#pragma unroll
        for (int s2 = 0; s2 < 8; ++s2) seg = comp2(maps8[sm * 8 + s2], seg);
        __hip_atomic_store(&ar[bid], FLG_AGG | seg,
                           __ATOMIC_RELAXED, __HIP_MEMORY_SCOPE_AGENT);
    }
    // ---- decoupled lookback: 8-wide windows, stop at first INCLUSIVE ----
    uint32_t prefix = ID8;
    {
        int wstart = bid - 8;
        bool done = (bid == 0);
        while (!done) {
            const int idx = wstart + ss;
            uint32_t w;
            if (idx < 0) {
                w = FLG_INC | ID8;
            } else {
                w = __hip_atomic_load(&ar[idx], __ATOMIC_RELAXED,
                                      __HIP_MEMORY_SCOPE_AGENT);
                while (!(w & 0xC0000000u)) {
                    __builtin_amdgcn_s_sleep(1);
                    w = __hip_atomic_load(&ar[idx], __ATOMIC_RELAXED,
                                          __HIP_MEMORY_SCOPE_AGENT);
                }
            }
            uint32_t cur = prefix;
            bool stop = false;
#pragma unroll
            for (int k = 7; k >= 0; --k) {
                const uint32_t wk = __shfl(w, (tid & 56) | k, 64);
                if (!stop) {
                    cur = comp2(cur, wk & 0xFFu);
                    if (wk & FLG_INC) stop = true;
                }
            }
            prefix = cur;
            done = stop;
            wstart -= 8;
        }
    }
    // ---- publish INCLUSIVE (flag bit31) ----
    if (ss == 0) {
        uint32_t Aown = ID8;
#pragma unroll
        for (int s2 = 0; s2 < 8; ++s2) Aown = comp2(maps8[sm * 8 + s2], Aown);
        __hip_atomic_store(&ar[bid], FLG_INC | comp2(Aown, prefix),
                           __ATOMIC_RELAXED, __HIP_MEMORY_SCOPE_AGENT);
    }
    // ---- within-block entry + sequential tanh over this subchunk (in LDS) ----
    {
        uint32_t s = (prefix >> 6) & 3u;   // prefix applied to initial state 3
        for (int k = 0; k < ss; ++k) s = (maps8[sm * 8 + k] >> (2 * s)) & 3u;
        float p = (s == 3u) ? spv : ((float)(int)s - 1.0f);
        float* yr = &xs[(sm * 8 + ss) * 33];
        for (int j = 0; j < st; ++j) {
            const float a = fmaf(p, pws, yr[j]);
            yr[j] = tanhf(a);
            p = sgnf(a);
        }
    }
    __syncthreads();
    // ---- coalesced final store (conv layout) ----
#pragma unroll
    for (int oi = 0; oi < 8; ++oi) {
        const int o = og * 8 + oi;
        float* orow = out + (size_t)o * OUT_W + 1 + base + lane;
#pragma unroll
        for (int tt = 0; tt < 4; ++tt) {
            const int t = base + lane + 64 * tt;
            const int sub = (lane >> 5) + 2 * tt;
            if (t < TY_LEN) orow[64 * tt] = xs[(o * 8 + sub) * 33 + (lane & 31)];
        }
    }
    if (bid == 0 && tid < NM)
        out[(size_t)tid * OUT_W] = sp[tid];
}

extern "C" void kernel_launch(void* const* d_in, const int* in_sizes, int n_in,
                              void* d_out, int out_size, void* d_ws, size_t ws_size,
                              hipStream_t stream)
{
    const float* x   = (const float*)d_in[0];
    const float* spv = (const float*)d_in[1];
    const float* w   = (const float*)d_in[2];
    const float* b   = (const float*)d_in[3];
    const float* pw  = (const float*)d_in[4];
    float* out = (float*)d_out;

    // workspace: wT2 64 KiB | agg 512 KiB (flag-tagged maps)
    uint8_t* ws = (uint8_t*)d_ws;
    float*    wT2 = (float*)ws;
    uint32_t* agg = (uint32_t*)(ws + 65536);

    wtrans_kernel<<<64, 256, 0, stream>>>(w, wT2, agg);
    conv_kernel<<<NBLK, CBT, 0, stream>>>(x, wT2, b, spv, pw, out, agg);
}

// Round 20
// 425.021 us; speedup vs baseline: 1.1238x; 1.1082x over previous
//
#include <hip/hip_runtime.h>
#include <stdint.h>

#define T_LEN    1048576
#define TY_LEN   1048561
#define OUT_W    1048562
#define NM       32
#define WIN      16
#define NBLK     4096    // conv blocks == 256-step chunks
#define CBT      256     // conv block threads (4 waves)
#define TPB      256     // timesteps per conv block (8 subchunks of 32)
#define XS_W     272     // 256 + 15 halo + pad; 32*272*4 = 34816 B
#define NF4      68      // XS_W/4 float4s per channel
#define ID8      0xE4u   // identity map, 2-bit packed: 0|1<<2|2<<4|3<<6
#define FLG_AGG  0x40000000u
#define FLG_INC  0x80000000u

__device__ inline float sgnf(float a){
    return (a > 0.0f) ? 1.0f : ((a < 0.0f) ? -1.0f : 0.0f);
}

// 2-bit-packed 4-state map composition: (f o g)(s) = f(g(s))
__device__ inline uint32_t comp2(uint32_t f, uint32_t g){
    uint32_t r = 0;
#pragma unroll
    for (int k = 0; k < 4; ++k) {
        const uint32_t s = (g >> (2 * k)) & 3u;
        r |= ((f >> (2 * s)) & 3u) << (2 * k);
    }
    return r;
}

// ---------------- weight relayout w[o][i][h] -> wT2[h][og][i][oi] + agg clear
__global__ void wtrans_kernel(const float* __restrict__ w, float* __restrict__ wT2,
                              uint32_t* __restrict__ agg){
    const int idx = blockIdx.x * 256 + threadIdx.x;
    if (idx < NM * NM * WIN) {
        const int o = idx / (NM * WIN);
        const int r = idx - o * (NM * WIN);
        const int i = r / WIN;
        const int h = r - i * WIN;
        wT2[(((h * 4) + (o >> 3)) * NM + i) * 8 + (o & 7)] = w[idx];
    }
    for (int j = idx; j < NM * NBLK; j += 64 * 256) agg[j] = 0;
}

// ---------------- fully fused: conv + scan maps + rocPRIM-style decoupled
// lookback (aggregate/inclusive two-flag) + tanh + final store.
// Conv order XLA-CPU-faithful (h-major, i-minor, bias last); FMA chain
// operand-identical to all passing rounds. y lives only in LDS.
__global__ __launch_bounds__(256, 4) void conv_kernel(
    const float* __restrict__ x, const float* __restrict__ wT2,
    const float* __restrict__ b, const float* __restrict__ sp,
    const float* __restrict__ pwv, float* __restrict__ out,
    uint32_t* __restrict__ agg)
{
    __shared__ float xs[NM * XS_W];   // staging; reused as y-stage [256][33]
    __shared__ uint32_t maps8[256];   // 8-bit local maps per (market, subchunk)
    const int bid  = blockIdx.x;
    const int base = bid * TPB;
    for (int idx = threadIdx.x; idx < NM * NF4; idx += CBT) {
        const int i = idx / NF4;
        const int q = idx - i * NF4;
        const int t0 = base + q * 4;
        float4 v;
        if (t0 + 3 < T_LEN) {
            v = *reinterpret_cast<const float4*>(x + (size_t)i * T_LEN + t0);
        } else {
            v.x = (t0 + 0 < T_LEN) ? x[(size_t)i * T_LEN + t0 + 0] : 0.0f;
            v.y = (t0 + 1 < T_LEN) ? x[(size_t)i * T_LEN + t0 + 1] : 0.0f;
            v.z = (t0 + 2 < T_LEN) ? x[(size_t)i * T_LEN + t0 + 2] : 0.0f;
            v.w = (t0 + 3 < T_LEN) ? x[(size_t)i * T_LEN + t0 + 3] : 0.0f;
        }
        *reinterpret_cast<float4*>(&xs[i * XS_W + q * 4]) = v;
    }
    __syncthreads();
    const int lane = threadIdx.x & 63;
    const int og   = __builtin_amdgcn_readfirstlane(threadIdx.x >> 6);
    float acc[8][4];
#pragma unroll
    for (int oi = 0; oi < 8; ++oi)
#pragma unroll
        for (int tt = 0; tt < 4; ++tt) acc[oi][tt] = 0.0f;
#pragma unroll 1
    for (int h = 0; h < WIN; ++h) {
        const float* wp = wT2 + (size_t)(h * 4 + og) * (NM * 8);  // uniform
#pragma unroll 1
        for (int c = 0; c < 4; ++c) {            // 8-i chunks
            float xv[8][4];
#pragma unroll
            for (int i2 = 0; i2 < 8; ++i2) {
                const int i = c * 8 + i2;
#pragma unroll
                for (int tt = 0; tt < 4; ++tt)
                    xv[i2][tt] = xs[i * XS_W + lane + 64 * tt + h];
            }
#pragma unroll
            for (int i2 = 0; i2 < 8; ++i2) {
                const float* wr = wp + (c * 8 + i2) * 8;   // 32 B, lane-uniform
#pragma unroll
                for (int oi = 0; oi < 8; ++oi) {
                    const float wv = wr[oi];
#pragma unroll
                    for (int tt = 0; tt < 4; ++tt)
                        acc[oi][tt] = fmaf(wv, xv[i2][tt], acc[oi][tt]);
                }
            }
        }
    }
    // ---- y = acc + bias -> LDS y-stage, subchunk-padded stride 33 ----
    __syncthreads();   // staging reads of xs complete before overwrite
#pragma unroll
    for (int oi = 0; oi < 8; ++oi) {
        const int o = og * 8 + oi;
        const float bv = b[o];
#pragma unroll
        for (int tt = 0; tt < 4; ++tt) {
            const int sub = (lane >> 5) + 2 * tt;          // t_local/32
            xs[(o * 8 + sub) * 33 + (lane & 31)] = acc[oi][tt] + bv;
        }
    }
    __syncthreads();
    // ---- local 32-step maps: thread = (market sm, subchunk ss) ----
    const int sm = threadIdx.x >> 3;
    const int ss = threadIdx.x & 7;
    const float pws = pwv[sm];
    const float spv = sp[sm];
    int st = TY_LEN - base - ss * 32;
    st = st < 0 ? 0 : (st > 32 ? 32 : st);
    {
        float q0 = -1.0f, q1 = 0.0f, q2 = 1.0f, q3 = spv;
        const float* yr = &xs[(sm * 8 + ss) * 33];
        for (int j = 0; j < st; ++j) {
            const float hv = yr[j];
            q0 = sgnf(fmaf(q0, pws, hv));
            q1 = sgnf(fmaf(q1, pws, hv));
            q2 = sgnf(fmaf(q2, pws, hv));
            q3 = sgnf(fmaf(q3, pws, hv));
        }
        const uint32_t e0 = (uint32_t)((int)q0 + 1);
        const uint32_t e1 = (uint32_t)((int)q1 + 1);
        const uint32_t e2 = (uint32_t)((int)q2 + 1);
        const uint32_t e3 = (st == 0) ? 3u : (uint32_t)((int)q3 + 1);
        maps8[threadIdx.x] = e0 | (e1 << 2) | (e2 << 4) | (e3 << 6);
    }
    __syncthreads();
    // ---- publish this block's AGGREGATE map per market (flag bit30) ----
    uint32_t* ar = agg + (size_t)sm * NBLK;
    if (ss == 0) {
        uint32_t seg = ID8;
#pragma unroll
        for (int s2 = 0; s2 < 8; ++s2) seg = comp2(maps8[sm * 8 + s2], seg);
        __hip_atomic_store(&ar[bid], FLG_AGG | seg,
                           __ATOMIC_RELAXED, __HIP_MEMORY_SCOPE_AGENT);
    }
    // ---- decoupled lookback: 8-wide windows, stop at first INCLUSIVE ----
    uint32_t prefix = ID8;
    {
        int wstart = bid - 8;
        bool done = (bid == 0);
        while (!done) {
            const int idx = wstart + ss;
            uint32_t w;
            if (idx < 0) {
                w = FLG_INC | ID8;     // virtual inclusive identity before block 0
            } else {
                w = __hip_atomic_load(&ar[idx], __ATOMIC_RELAXED,
                                      __HIP_MEMORY_SCOPE_AGENT);
                while (!(w & 0xC0000000u)) {
                    __builtin_amdgcn_s_sleep(1);
                    w = __hip_atomic_load(&ar[idx], __ATOMIC_RELAXED,
                                          __HIP_MEMORY_SCOPE_AGENT);
                }
            }
            // all 8 lanes of this market compose the window redundantly
            uint32_t cur = prefix;
            bool stop = false;
#pragma unroll
            for (int k = 7; k >= 0; --k) {
                const uint32_t wk = __shfl(w, (threadIdx.x & 56) | k, 64);
                if (!stop) {
                    cur = comp2(cur, wk & 0xFFu);
                    if (wk & FLG_INC) stop = true;
                }
            }
            prefix = cur;
            done = stop;
            wstart -= 8;
        }
    }
    // ---- publish INCLUSIVE prefix (flag bit31) ----
    if (ss == 0) {
        uint32_t Aown = ID8;
#pragma unroll
        for (int s2 = 0; s2 < 8; ++s2) Aown = comp2(maps8[sm * 8 + s2], Aown);
        __hip_atomic_store(&ar[bid], FLG_INC | comp2(Aown, prefix),
                           __ATOMIC_RELAXED, __HIP_MEMORY_SCOPE_AGENT);
    }
    // ---- within-block entry + sequential tanh over this subchunk (in LDS) ----
    {
        uint32_t s = (prefix >> 6) & 3u;   // prefix applied to initial state 3
        for (int k = 0; k < ss; ++k) s = (maps8[sm * 8 + k] >> (2 * s)) & 3u;
        float p = (s == 3u) ? spv : ((float)(int)s - 1.0f);
        float* yr = &xs[(sm * 8 + ss) * 33];
        for (int j = 0; j < st; ++j) {
            const float a = fmaf(p, pws, yr[j]);
            yr[j] = tanhf(a);
            p = sgnf(a);
        }
    }
    __syncthreads();
    // ---- coalesced final store (conv layout) ----
#pragma unroll
    for (int oi = 0; oi < 8; ++oi) {
        const int o = og * 8 + oi;
        float* orow = out + (size_t)o * OUT_W + 1 + base + lane;
#pragma unroll
        for (int tt = 0; tt < 4; ++tt) {
            const int t = base + lane + 64 * tt;
            const int sub = (lane >> 5) + 2 * tt;
            if (t < TY_LEN) orow[64 * tt] = xs[(o * 8 + sub) * 33 + (lane & 31)];
        }
    }
    if (bid == 0 && threadIdx.x < NM)
        out[(size_t)threadIdx.x * OUT_W] = sp[threadIdx.x];
}

extern "C" void kernel_launch(void* const* d_in, const int* in_sizes, int n_in,
                              void* d_out, int out_size, void* d_ws, size_t ws_size,
                              hipStream_t stream)
{
    const float* x   = (const float*)d_in[0];
    const float* spv = (const float*)d_in[1];
    const float* w   = (const float*)d_in[2];
    const float* b   = (const float*)d_in[3];
    const float* pw  = (const float*)d_in[4];
    float* out = (float*)d_out;

    // workspace: wT2 64 KiB | agg 512 KiB (flag-tagged maps)
    uint8_t* ws = (uint8_t*)d_ws;
    float*    wT2 = (float*)ws;
    uint32_t* agg = (uint32_t*)(ws + 65536);

    wtrans_kernel<<<64, 256, 0, stream>>>(w, wT2, agg);
    conv_kernel<<<NBLK, CBT, 0, stream>>>(x, wT2, b, spv, pw, out, agg);
}